// Round 1
// baseline (479.700 us; speedup 1.0000x reference)
//
#include <hip/hip_runtime.h>
#include <stdint.h>

// ---------- types ----------
typedef __attribute__((ext_vector_type(8))) short   short8;
typedef __attribute__((ext_vector_type(8))) __bf16  bf16x8;
typedef __attribute__((ext_vector_type(4))) float   floatx4;

#define DEV static __device__ __forceinline__

// f32 -> bf16 (RNE) raw bits
DEV unsigned short f2b(float f) {
  union { float f; unsigned u; } v; v.f = f;
  unsigned u = v.u;
  unsigned r = u + 0x7FFFu + ((u >> 16) & 1u);
  return (unsigned short)(r >> 16);
}
DEV float b2f(unsigned short s) {
  union { unsigned u; float f; } v; v.u = ((unsigned)s) << 16;
  return v.f;
}

// async global->LDS, 16 bytes per lane. LDS dest must be wave-uniform base + lane*16.
DEV void gload_lds16(const void* g, void* l) {
  __builtin_amdgcn_global_load_lds(
      (const __attribute__((address_space(1))) unsigned int*)g,
      (__attribute__((address_space(3))) unsigned int*)l,
      16, 0, 0);
}

// ---------- elementwise f32->bf16 convert ----------
__global__ void cvt_kernel(const float* __restrict__ in, unsigned short* __restrict__ out, int n4) {
  int i = blockIdx.x * blockDim.x + threadIdx.x;
  if (i >= n4) return;
  float4 v = ((const float4*)in)[i];
  ushort4 o;
  o.x = f2b(v.x); o.y = f2b(v.y); o.z = f2b(v.z); o.w = f2b(v.w);
  ((ushort4*)out)[i] = o;
}

// ---------- H [16][2048][1280] f32  ->  HT [16][1280][2048] bf16 ----------
__global__ void transpose_cvt_H(const float* __restrict__ H, unsigned short* __restrict__ HT) {
  __shared__ unsigned short tile[64 * 68];   // 64 l-rows x 64 d-cols, pad to 68 (8B-aligned rows, odd-ish bank stride)
  const int b  = blockIdx.z;
  const int l0 = blockIdx.x * 64;
  const int d0 = blockIdx.y * 64;
  const int t  = threadIdx.x;

  // phase 1: coalesced f32 reads, convert, LDS write
  {
    int row = t >> 2;          // l offset 0..63
    int seg = t & 3;           // 16-float segment
    const float* src = H + ((size_t)b * 2048 + l0 + row) * 1280 + d0 + seg * 16;
#pragma unroll
    for (int s = 0; s < 4; ++s) {
      float4 v = *(const float4*)(src + s * 4);
      ushort4 o;
      o.x = f2b(v.x); o.y = f2b(v.y); o.z = f2b(v.z); o.w = f2b(v.w);
      *(ushort4*)&tile[row * 68 + seg * 16 + s * 4] = o;
    }
  }
  __syncthreads();
  // phase 2: read columns, 16B vector stores along L
  {
    int dr = t >> 2;           // d offset 0..63
    int ls = (t & 3) * 16;     // l segment
    unsigned short* dst = HT + ((size_t)b * 1280 + d0 + dr) * 2048 + l0 + ls;
    short8 a, c;
#pragma unroll
    for (int i = 0; i < 8; ++i) a[i] = (short)tile[(ls + i) * 68 + dr];
#pragma unroll
    for (int i = 0; i < 8; ++i) c[i] = (short)tile[(ls + 8 + i) * 68 + dr];
    *(short8*)dst = a;
    *(short8*)(dst + 8) = c;
  }
}

// ---------- row sum of E (bf16) -> 1/sum (f32), one wave per row ----------
__global__ void rowsum_inv_kernel(const unsigned short* __restrict__ E, float* __restrict__ linv, int rowlen) {
  int row  = blockIdx.x * 4 + (threadIdx.x >> 6);
  int lane = threadIdx.x & 63;
  const unsigned short* p = E + (size_t)row * rowlen;
  float s = 0.f;
  for (int c = lane * 8; c < rowlen; c += 512) {
    short8 v = *(const short8*)(p + c);
#pragma unroll
    for (int k = 0; k < 8; ++k) s += b2f((unsigned short)v[k]);
  }
#pragma unroll
  for (int off = 32; off > 0; off >>= 1) s += __shfl_down(s, off, 64);
  if (lane == 0) linv[row] = 1.0f / s;
}

// ---------- NT GEMM: C[M][N] = A[M][K] * Bt[N][K]^T, bf16 MFMA 16x16x32 ----------
// AMODE: 0 = A is bf16 (global_load_lds), 1 = A is f32 (register convert staging)
// EPI:   0 = store bf16, 1 = store bf16 of exp(v*escale), 2 = store f32 of v*linv[row]
template <int AMODE, int EPI>
__global__ void gemm_nt(const void* __restrict__ Apv, const unsigned short* __restrict__ Btb,
                        void* __restrict__ Cpv, const float* __restrict__ linvb,
                        int M, int N, int K, int lda, int ldb, int ldc,
                        long long sA, long long sB, long long sC, int sL, float escale) {
  __shared__ unsigned short As[128 * 32];
  __shared__ unsigned short Bs[128 * 32];

  const int bz  = blockIdx.z;
  const int m0  = blockIdx.y * 128;
  const int n0  = blockIdx.x * 128;
  const int t   = threadIdx.x;
  const int lane = t & 63;
  const int wave = t >> 6;
  const int wm  = (wave & 1) * 64;
  const int wn  = (wave >> 1) * 64;
  const int r16 = lane & 15;
  const int q   = lane >> 4;

  const unsigned short* Bt = Btb + (long long)bz * sB;
  const unsigned short* Abf = (const unsigned short*)Apv + (long long)bz * sA;
  const float* A32 = (const float*)Apv + (long long)bz * sA;

  floatx4 acc[4][4];
#pragma unroll
  for (int i = 0; i < 4; ++i)
#pragma unroll
    for (int j = 0; j < 4; ++j) acc[i][j] = (floatx4){0.f, 0.f, 0.f, 0.f};

  for (int kt = 0; kt < K; kt += 32) {
    __syncthreads();
    // stage B tile [128 n][32 k] -> Bs row-major, 512 chunks of 8 bf16
#pragma unroll
    for (int cc = 0; cc < 2; ++cc) {
      int c = t + cc * 256;
      gload_lds16(Bt + (size_t)(n0 + (c >> 2)) * ldb + kt + (c & 3) * 8, &Bs[c * 8]);
    }
    // stage A tile
    if constexpr (AMODE == 0) {
#pragma unroll
      for (int cc = 0; cc < 2; ++cc) {
        int c = t + cc * 256;
        gload_lds16(Abf + (size_t)(m0 + (c >> 2)) * lda + kt + (c & 3) * 8, &As[c * 8]);
      }
    } else {
#pragma unroll
      for (int cc = 0; cc < 2; ++cc) {
        int c = t + cc * 256;
        const float* g = A32 + (size_t)(m0 + (c >> 2)) * lda + kt + (c & 3) * 8;
        float4 v0 = *(const float4*)g;
        float4 v1 = *(const float4*)(g + 4);
        short8 p;
        p[0] = (short)f2b(v0.x); p[1] = (short)f2b(v0.y);
        p[2] = (short)f2b(v0.z); p[3] = (short)f2b(v0.w);
        p[4] = (short)f2b(v1.x); p[5] = (short)f2b(v1.y);
        p[6] = (short)f2b(v1.z); p[7] = (short)f2b(v1.w);
        *(short8*)&As[c * 8] = p;
      }
    }
    __syncthreads();

    bf16x8 af[4], bfr[4];
#pragma unroll
    for (int i = 0; i < 4; ++i) af[i]  = *(const bf16x8*)&As[(wm + i * 16 + r16) * 32 + q * 8];
#pragma unroll
    for (int j = 0; j < 4; ++j) bfr[j] = *(const bf16x8*)&Bs[(wn + j * 16 + r16) * 32 + q * 8];
#pragma unroll
    for (int i = 0; i < 4; ++i)
#pragma unroll
      for (int j = 0; j < 4; ++j)
        acc[i][j] = __builtin_amdgcn_mfma_f32_16x16x32_bf16(af[i], bfr[j], acc[i][j], 0, 0, 0);
  }

  // epilogue: D[m][n], m = q*4 + reg (+16*i + wm), n = r16 (+16*j + wn)
  if constexpr (EPI == 0 || EPI == 1) {
    unsigned short* C = (unsigned short*)Cpv + (long long)bz * sC;
#pragma unroll
    for (int i = 0; i < 4; ++i) {
#pragma unroll
      for (int r = 0; r < 4; ++r) {
        int m = m0 + wm + i * 16 + q * 4 + r;
#pragma unroll
        for (int j = 0; j < 4; ++j) {
          int n = n0 + wn + j * 16 + r16;
          float v = acc[i][j][r];
          if (EPI == 1) v = __expf(v * escale);
          C[(size_t)m * ldc + n] = f2b(v);
        }
      }
    }
  } else {
    float* C = (float*)Cpv + (long long)bz * sC;
    const float* linv = linvb + (long long)bz * sL;
#pragma unroll
    for (int i = 0; i < 4; ++i) {
#pragma unroll
      for (int r = 0; r < 4; ++r) {
        int m = m0 + wm + i * 16 + q * 4 + r;
        float sc = linv[m];
#pragma unroll
        for (int j = 0; j < 4; ++j) {
          int n = n0 + wn + j * 16 + r16;
          C[(size_t)m * ldc + n] = acc[i][j][r] * sc;
        }
      }
    }
  }
}

// ---------- launch ----------
extern "C" void kernel_launch(void* const* d_in, const int* in_sizes, int n_in,
                              void* d_out, int out_size, void* d_ws, size_t ws_size,
                              hipStream_t stream) {
  (void)in_sizes; (void)n_in; (void)out_size; (void)ws_size;
  const float* H  = (const float*)d_in[0];   // [16][2048][1280]
  const float* G  = (const float*)d_in[1];   // [16][512][768]
  const float* Wq = (const float*)d_in[2];   // [256][768]
  const float* Wk = (const float*)d_in[3];   // [256][1280]
  float* Z = (float*)d_out;                  // [16][512][1280]

  constexpr int B = 16, L = 2048, Dh = 1280, T = 512, Dg = 768, P = 256;

  char* ws = (char*)d_ws;
  size_t off = 0;
  auto alloc = [&](size_t bytes) { void* p = ws + off; off += (bytes + 255) & ~(size_t)255; return p; };
  unsigned short* Gbf  = (unsigned short*)alloc((size_t)B * T * Dg * 2);   // 12.6 MB
  unsigned short* Wqbf = (unsigned short*)alloc((size_t)P * Dg * 2);
  unsigned short* Wkbf = (unsigned short*)alloc((size_t)P * Dh * 2);
  unsigned short* Qbf  = (unsigned short*)alloc((size_t)B * T * P * 2);    // 4 MB
  unsigned short* Kbf  = (unsigned short*)alloc((size_t)B * L * P * 2);    // 16 MB
  unsigned short* HT   = (unsigned short*)alloc((size_t)B * Dh * L * 2);   // 80 MB
  unsigned short* E    = (unsigned short*)alloc((size_t)B * T * L * 2);    // 32 MB
  float*          linv = (float*)alloc((size_t)B * T * 4);
  // total ~145 MB of ws

  // converts
  cvt_kernel<<<(B * T * Dg / 4 + 255) / 256, 256, 0, stream>>>(G, Gbf, B * T * Dg / 4);
  cvt_kernel<<<(P * Dg / 4 + 255) / 256, 256, 0, stream>>>(Wq, Wqbf, P * Dg / 4);
  cvt_kernel<<<(P * Dh / 4 + 255) / 256, 256, 0, stream>>>(Wk, Wkbf, P * Dh / 4);
  transpose_cvt_H<<<dim3(L / 64, Dh / 64, B), 256, 0, stream>>>(H, HT);

  // Q = Gbf * Wqbf^T : [8192][256]
  gemm_nt<0, 0><<<dim3(P / 128, B * T / 128, 1), 256, 0, stream>>>(
      Gbf, Wqbf, Qbf, nullptr, B * T, P, Dg, Dg, Dg, P, 0, 0, 0, 0, 0.f);
  // K = H(f32) * Wkbf^T : [32768][256]
  gemm_nt<1, 0><<<dim3(P / 128, B * L / 128, 1), 256, 0, stream>>>(
      H, Wkbf, Kbf, nullptr, B * L, P, Dh, Dh, Dh, P, 0, 0, 0, 0, 0.f);
  // E = exp(scale * Qb * Kb^T) : per b [512][2048]
  gemm_nt<0, 1><<<dim3(L / 128, T / 128, B), 256, 0, stream>>>(
      Qbf, Kbf, E, nullptr, T, L, P, P, P, L,
      (long long)T * P, (long long)L * P, (long long)T * L, 0, 0.0625f);
  // linv = 1 / rowsum(E)
  rowsum_inv_kernel<<<B * T / 4, 256, 0, stream>>>(E, linv, L);
  // Z = diag(linv) * Eb * HTb^T : per b [512][1280] f32
  gemm_nt<0, 2><<<dim3(Dh / 128, T / 128, B), 256, 0, stream>>>(
      E, HT, Z, linv, T, Dh, L, L, L, Dh,
      (long long)T * L, (long long)Dh * L, (long long)T * Dh, T, 0.f);
}

// Round 2
// 472.787 us; speedup vs baseline: 1.0146x; 1.0146x over previous
//
#include <hip/hip_runtime.h>
#include <stdint.h>

// ---------- types ----------
typedef __attribute__((ext_vector_type(8))) short   short8;
typedef __attribute__((ext_vector_type(8))) __bf16  bf16x8;
typedef __attribute__((ext_vector_type(4))) float   floatx4;

#define DEV static __device__ __forceinline__

// f32 -> bf16 (RNE) raw bits
DEV unsigned short f2b(float f) {
  union { float f; unsigned u; } v; v.f = f;
  unsigned u = v.u;
  unsigned r = u + 0x7FFFu + ((u >> 16) & 1u);
  return (unsigned short)(r >> 16);
}
DEV float b2f(unsigned short s) {
  union { unsigned u; float f; } v; v.u = ((unsigned)s) << 16;
  return v.f;
}

// async global->LDS, 16 bytes per lane. LDS dest must be wave-uniform base + lane*16.
DEV void gload_lds16(const void* g, void* l) {
  __builtin_amdgcn_global_load_lds(
      (const __attribute__((address_space(1))) unsigned int*)g,
      (__attribute__((address_space(3))) unsigned int*)l,
      16, 0, 0);
}

// ---------- elementwise f32->bf16 convert ----------
__global__ void cvt_kernel(const float* __restrict__ in, unsigned short* __restrict__ out, int n4) {
  int i = blockIdx.x * blockDim.x + threadIdx.x;
  if (i >= n4) return;
  float4 v = ((const float4*)in)[i];
  ushort4 o;
  o.x = f2b(v.x); o.y = f2b(v.y); o.z = f2b(v.z); o.w = f2b(v.w);
  ((ushort4*)out)[i] = o;
}

// ---------- H [16][2048][1280] f32  ->  HT [16][1280][2048] bf16 ----------
__global__ void transpose_cvt_H(const float* __restrict__ H, unsigned short* __restrict__ HT) {
  __shared__ unsigned short tile[64 * 68];   // 64 l-rows x 64 d-cols, padded
  const int b  = blockIdx.z;
  const int l0 = blockIdx.x * 64;
  const int d0 = blockIdx.y * 64;
  const int t  = threadIdx.x;

  // phase 1: coalesced f32 reads, convert, LDS write
  {
    int row = t >> 2;          // l offset 0..63
    int seg = t & 3;           // 16-float segment
    const float* src = H + ((size_t)b * 2048 + l0 + row) * 1280 + d0 + seg * 16;
#pragma unroll
    for (int s = 0; s < 4; ++s) {
      float4 v = *(const float4*)(src + s * 4);
      ushort4 o;
      o.x = f2b(v.x); o.y = f2b(v.y); o.z = f2b(v.z); o.w = f2b(v.w);
      *(ushort4*)&tile[row * 68 + seg * 16 + s * 4] = o;
    }
  }
  __syncthreads();
  // phase 2: read columns, 16B vector stores along L
  {
    int dr = t >> 2;           // d offset 0..63
    int ls = (t & 3) * 16;     // l segment
    unsigned short* dst = HT + ((size_t)b * 1280 + d0 + dr) * 2048 + l0 + ls;
    short8 a, c;
#pragma unroll
    for (int i = 0; i < 8; ++i) a[i] = (short)tile[(ls + i) * 68 + dr];
#pragma unroll
    for (int i = 0; i < 8; ++i) c[i] = (short)tile[(ls + 8 + i) * 68 + dr];
    *(short8*)dst = a;
    *(short8*)(dst + 8) = c;
  }
}

// ---------- row sum of E (bf16) -> 1/sum (f32), one wave per row ----------
__global__ void rowsum_inv_kernel(const unsigned short* __restrict__ E, float* __restrict__ linv, int rowlen) {
  int row  = blockIdx.x * 4 + (threadIdx.x >> 6);
  int lane = threadIdx.x & 63;
  const unsigned short* p = E + (size_t)row * rowlen;
  float s = 0.f;
  for (int c = lane * 8; c < rowlen; c += 512) {
    short8 v = *(const short8*)(p + c);
#pragma unroll
    for (int k = 0; k < 8; ++k) s += b2f((unsigned short)v[k]);
  }
#pragma unroll
  for (int off = 32; off > 0; off >>= 1) s += __shfl_down(s, off, 64);
  if (lane == 0) linv[row] = 1.0f / s;
}

// ---------- projection GEMM: C[M][256] = A[M][K] * Bt[256][K]^T ----------
// Tile: 64 m x 256 n per block (full N in one block => A fetched exactly once).
// 4 waves; wave w covers n in [w*64, w*64+64), all 64 m.
// AMODE: 0 = A bf16 (global_load_lds), 1 = A f32 (register-convert staging)
template <int AMODE>
__global__ void proj_gemm(const void* __restrict__ Apv, const unsigned short* __restrict__ Bt,
                          unsigned short* __restrict__ C, int K, int lda) {
  __shared__ unsigned short As[64 * 32];    // 4 KB
  __shared__ unsigned short Bs[256 * 32];   // 16 KB

  const int m0   = blockIdx.x * 64;
  const int t    = threadIdx.x;
  const int lane = t & 63;
  const int wave = t >> 6;
  const int wn   = wave * 64;
  const int r16  = lane & 15;
  const int q    = lane >> 4;

  const unsigned short* Abf = (const unsigned short*)Apv;
  const float* A32 = (const float*)Apv;

  floatx4 acc[4][4];
#pragma unroll
  for (int i = 0; i < 4; ++i)
#pragma unroll
    for (int j = 0; j < 4; ++j) acc[i][j] = (floatx4){0.f, 0.f, 0.f, 0.f};

  for (int kt = 0; kt < K; kt += 32) {
    __syncthreads();
    // stage B tile [256 n][32 k]: 1024 16B chunks
#pragma unroll
    for (int cc = 0; cc < 4; ++cc) {
      int c = t + cc * 256;
      gload_lds16(Bt + (size_t)(c >> 2) * K + kt + (c & 3) * 8, &Bs[c * 8]);
    }
    // stage A tile [64 m][32 k]: 256 chunks
    if constexpr (AMODE == 0) {
      gload_lds16(Abf + (size_t)(m0 + (t >> 2)) * lda + kt + (t & 3) * 8, &As[t * 8]);
    } else {
      const float* g = A32 + (size_t)(m0 + (t >> 2)) * lda + kt + (t & 3) * 8;
      float4 v0 = *(const float4*)g;
      float4 v1 = *(const float4*)(g + 4);
      short8 p;
      p[0] = (short)f2b(v0.x); p[1] = (short)f2b(v0.y);
      p[2] = (short)f2b(v0.z); p[3] = (short)f2b(v0.w);
      p[4] = (short)f2b(v1.x); p[5] = (short)f2b(v1.y);
      p[6] = (short)f2b(v1.z); p[7] = (short)f2b(v1.w);
      *(short8*)&As[t * 8] = p;
    }
    __syncthreads();

    bf16x8 af[4], bfr[4];
#pragma unroll
    for (int i = 0; i < 4; ++i) af[i]  = *(const bf16x8*)&As[(i * 16 + r16) * 32 + q * 8];
#pragma unroll
    for (int j = 0; j < 4; ++j) bfr[j] = *(const bf16x8*)&Bs[(wn + j * 16 + r16) * 32 + q * 8];
#pragma unroll
    for (int i = 0; i < 4; ++i)
#pragma unroll
      for (int j = 0; j < 4; ++j)
        acc[i][j] = __builtin_amdgcn_mfma_f32_16x16x32_bf16(af[i], bfr[j], acc[i][j], 0, 0, 0);
  }

  // epilogue: bf16 store, ldc = 256
#pragma unroll
  for (int i = 0; i < 4; ++i) {
#pragma unroll
    for (int r = 0; r < 4; ++r) {
      int m = m0 + i * 16 + q * 4 + r;
#pragma unroll
      for (int j = 0; j < 4; ++j) {
        int n = wn + j * 16 + r16;
        C[(size_t)m * 256 + n] = f2b(acc[i][j][r]);
      }
    }
  }
}

// ---------- NT GEMM: C[M][N] = A[M][K] * Bt[N][K]^T, bf16, 128x128 tile ----------
// EPI: 1 = store bf16 of exp(v*escale), 2 = store f32 of v*linv[row]
template <int EPI>
__global__ void gemm_nt(const unsigned short* __restrict__ Ab, const unsigned short* __restrict__ Btb,
                        void* __restrict__ Cpv, const float* __restrict__ linvb,
                        int K, int lda, int ldb, int ldc,
                        long long sA, long long sB, long long sC, int sL, float escale) {
  __shared__ unsigned short As[128 * 32];
  __shared__ unsigned short Bs[128 * 32];

  const int bz  = blockIdx.z;
  const int m0  = blockIdx.y * 128;
  const int n0  = blockIdx.x * 128;
  const int t   = threadIdx.x;
  const int lane = t & 63;
  const int wave = t >> 6;
  const int wm  = (wave & 1) * 64;
  const int wn  = (wave >> 1) * 64;
  const int r16 = lane & 15;
  const int q   = lane >> 4;

  const unsigned short* Bt = Btb + (long long)bz * sB;
  const unsigned short* A  = Ab + (long long)bz * sA;

  floatx4 acc[4][4];
#pragma unroll
  for (int i = 0; i < 4; ++i)
#pragma unroll
    for (int j = 0; j < 4; ++j) acc[i][j] = (floatx4){0.f, 0.f, 0.f, 0.f};

  for (int kt = 0; kt < K; kt += 32) {
    __syncthreads();
#pragma unroll
    for (int cc = 0; cc < 2; ++cc) {
      int c = t + cc * 256;
      gload_lds16(Bt + (size_t)(n0 + (c >> 2)) * ldb + kt + (c & 3) * 8, &Bs[c * 8]);
    }
#pragma unroll
    for (int cc = 0; cc < 2; ++cc) {
      int c = t + cc * 256;
      gload_lds16(A + (size_t)(m0 + (c >> 2)) * lda + kt + (c & 3) * 8, &As[c * 8]);
    }
    __syncthreads();

    bf16x8 af[4], bfr[4];
#pragma unroll
    for (int i = 0; i < 4; ++i) af[i]  = *(const bf16x8*)&As[(wm + i * 16 + r16) * 32 + q * 8];
#pragma unroll
    for (int j = 0; j < 4; ++j) bfr[j] = *(const bf16x8*)&Bs[(wn + j * 16 + r16) * 32 + q * 8];
#pragma unroll
    for (int i = 0; i < 4; ++i)
#pragma unroll
      for (int j = 0; j < 4; ++j)
        acc[i][j] = __builtin_amdgcn_mfma_f32_16x16x32_bf16(af[i], bfr[j], acc[i][j], 0, 0, 0);
  }

  // epilogue: D[m][n], m = q*4 + reg (+16*i + wm), n = r16 (+16*j + wn)
  if constexpr (EPI == 1) {
    unsigned short* C = (unsigned short*)Cpv + (long long)bz * sC;
#pragma unroll
    for (int i = 0; i < 4; ++i) {
#pragma unroll
      for (int r = 0; r < 4; ++r) {
        int m = m0 + wm + i * 16 + q * 4 + r;
#pragma unroll
        for (int j = 0; j < 4; ++j) {
          int n = n0 + wn + j * 16 + r16;
          C[(size_t)m * ldc + n] = f2b(__expf(acc[i][j][r] * escale));
        }
      }
    }
  } else {
    float* C = (float*)Cpv + (long long)bz * sC;
    const float* linv = linvb + (long long)bz * sL;
#pragma unroll
    for (int i = 0; i < 4; ++i) {
#pragma unroll
      for (int r = 0; r < 4; ++r) {
        int m = m0 + wm + i * 16 + q * 4 + r;
        float sc = linv[m];
#pragma unroll
        for (int j = 0; j < 4; ++j) {
          int n = n0 + wn + j * 16 + r16;
          C[(size_t)m * ldc + n] = acc[i][j][r] * sc;
        }
      }
    }
  }
}

// ---------- launch ----------
extern "C" void kernel_launch(void* const* d_in, const int* in_sizes, int n_in,
                              void* d_out, int out_size, void* d_ws, size_t ws_size,
                              hipStream_t stream) {
  (void)in_sizes; (void)n_in; (void)out_size; (void)ws_size;
  const float* H  = (const float*)d_in[0];   // [16][2048][1280]
  const float* G  = (const float*)d_in[1];   // [16][512][768]
  const float* Wq = (const float*)d_in[2];   // [256][768]
  const float* Wk = (const float*)d_in[3];   // [256][1280]
  float* Z = (float*)d_out;                  // [16][512][1280]

  constexpr int B = 16, L = 2048, Dh = 1280, T = 512, Dg = 768, P = 256;

  char* ws = (char*)d_ws;
  size_t off = 0;
  auto alloc = [&](size_t bytes) { void* p = ws + off; off += (bytes + 255) & ~(size_t)255; return p; };
  unsigned short* Gbf  = (unsigned short*)alloc((size_t)B * T * Dg * 2);   // 12.6 MB
  unsigned short* Wqbf = (unsigned short*)alloc((size_t)P * Dg * 2);
  unsigned short* Wkbf = (unsigned short*)alloc((size_t)P * Dh * 2);
  unsigned short* Qbf  = (unsigned short*)alloc((size_t)B * T * P * 2);    // 4 MB
  unsigned short* Kbf  = (unsigned short*)alloc((size_t)B * L * P * 2);    // 16 MB
  unsigned short* HT   = (unsigned short*)alloc((size_t)B * Dh * L * 2);   // 80 MB
  unsigned short* E    = (unsigned short*)alloc((size_t)B * T * L * 2);    // 32 MB
  float*          linv = (float*)alloc((size_t)B * T * 4);
  // total ~145 MB of ws

  // converts
  cvt_kernel<<<(B * T * Dg / 4 + 255) / 256, 256, 0, stream>>>(G, Gbf, B * T * Dg / 4);
  cvt_kernel<<<(P * Dg / 4 + 255) / 256, 256, 0, stream>>>(Wq, Wqbf, P * Dg / 4);
  cvt_kernel<<<(P * Dh / 4 + 255) / 256, 256, 0, stream>>>(Wk, Wkbf, P * Dh / 4);
  transpose_cvt_H<<<dim3(L / 64, Dh / 64, B), 256, 0, stream>>>(H, HT);

  // Q = Gbf * Wqbf^T : [8192][256], A fetched once (full-N tile)
  proj_gemm<0><<<B * T / 64, 256, 0, stream>>>(Gbf, Wqbf, Qbf, Dg, Dg);
  // K = H(f32) * Wkbf^T : [32768][256], H fetched once
  proj_gemm<1><<<B * L / 64, 256, 0, stream>>>(H, Wkbf, Kbf, Dh, Dh);
  // E = exp(scale * Qb * Kb^T) : per b [512][2048]
  gemm_nt<1><<<dim3(L / 128, T / 128, B), 256, 0, stream>>>(
      Qbf, Kbf, E, nullptr, P, P, P, L,
      (long long)T * P, (long long)L * P, (long long)T * L, 0, 0.0625f);
  // linv = 1 / rowsum(E)
  rowsum_inv_kernel<<<B * T / 4, 256, 0, stream>>>(E, linv, L);
  // Z = diag(linv) * Eb * HTb^T : per b [512][1280] f32
  gemm_nt<2><<<dim3(Dh / 128, T / 128, B), 256, 0, stream>>>(
      E, HT, Z, linv, P * 0 + L, L, L, Dh,
      (long long)T * L, (long long)Dh * L, (long long)T * Dh, T, 0.f);
}

// Round 3
// 444.174 us; speedup vs baseline: 1.0800x; 1.0644x over previous
//
#include <hip/hip_runtime.h>
#include <stdint.h>

// ---------- types ----------
typedef __attribute__((ext_vector_type(8))) short   short8;
typedef __attribute__((ext_vector_type(8))) __bf16  bf16x8;
typedef __attribute__((ext_vector_type(4))) float   floatx4;

#define DEV static __device__ __forceinline__

// f32 -> bf16 (RNE) raw bits
DEV unsigned short f2b(float f) {
  union { float f; unsigned u; } v; v.f = f;
  unsigned u = v.u;
  unsigned r = u + 0x7FFFu + ((u >> 16) & 1u);
  return (unsigned short)(r >> 16);
}

// async global->LDS, 16 bytes per lane. LDS dest must be wave-uniform base + lane*16.
DEV void gload_lds16(const void* g, void* l) {
  __builtin_amdgcn_global_load_lds(
      (const __attribute__((address_space(1))) unsigned int*)g,
      (__attribute__((address_space(3))) unsigned int*)l,
      16, 0, 0);
}

// ---------- fused f32->bf16 convert for G, Wq, Wk ----------
__global__ void cvt3_kernel(const float* __restrict__ a, unsigned short* __restrict__ oa, int na4,
                            const float* __restrict__ b, unsigned short* __restrict__ ob, int nb4,
                            const float* __restrict__ c, unsigned short* __restrict__ oc, int nc4) {
  int i = blockIdx.x * blockDim.x + threadIdx.x;
  const float* src; unsigned short* dst; int k;
  if (i < na4)                { src = a; dst = oa; k = i; }
  else if (i < na4 + nb4)     { src = b; dst = ob; k = i - na4; }
  else if (i < na4 + nb4 + nc4) { src = c; dst = oc; k = i - na4 - nb4; }
  else return;
  float4 v = ((const float4*)src)[k];
  ushort4 o;
  o.x = f2b(v.x); o.y = f2b(v.y); o.z = f2b(v.z); o.w = f2b(v.w);
  ((ushort4*)dst)[k] = o;
}

// ---------- zero-init row sums ----------
__global__ void zero_kernel(float* __restrict__ p, int n) {
  int i = blockIdx.x * blockDim.x + threadIdx.x;
  if (i < n) p[i] = 0.f;
}

// ---------- H [16][2048][1280] f32  ->  HT [16][1280][2048] bf16 ----------
// PAD=66 (odd word stride) => phase-2 column reads ~2-way bank aliasing (free).
__global__ void transpose_cvt_H(const float* __restrict__ H, unsigned short* __restrict__ HT) {
  __shared__ unsigned short tile[64 * 66];
  const int b  = blockIdx.z;
  const int l0 = blockIdx.x * 64;
  const int d0 = blockIdx.y * 64;
  const int t  = threadIdx.x;

  // phase 1: coalesced f32 reads, convert, LDS write (ushort2 = 4B aligned)
  {
    int row = t >> 2;          // l offset 0..63
    int seg = t & 3;           // 16-float segment
    const float* src = H + ((size_t)b * 2048 + l0 + row) * 1280 + d0 + seg * 16;
    unsigned short* trow = &tile[row * 66 + seg * 16];
#pragma unroll
    for (int s = 0; s < 4; ++s) {
      float4 v = *(const float4*)(src + s * 4);
      ushort2 p0 = { f2b(v.x), f2b(v.y) };
      ushort2 p1 = { f2b(v.z), f2b(v.w) };
      *(ushort2*)&trow[s * 4]     = p0;
      *(ushort2*)&trow[s * 4 + 2] = p1;
    }
  }
  __syncthreads();
  // phase 2: read columns, 16B vector stores along L
  {
    int dr = t >> 2;           // d offset 0..63
    int ls = (t & 3) * 16;     // l segment
    unsigned short* dst = HT + ((size_t)b * 1280 + d0 + dr) * 2048 + l0 + ls;
    short8 a, c;
#pragma unroll
    for (int i = 0; i < 8; ++i) a[i] = (short)tile[(ls + i) * 66 + dr];
#pragma unroll
    for (int i = 0; i < 8; ++i) c[i] = (short)tile[(ls + 8 + i) * 66 + dr];
    *(short8*)dst = a;
    *(short8*)(dst + 8) = c;
  }
}

// ---------- projection GEMM: C[M][256] = A[M][K] * Bt[256][K]^T ----------
// 64 m x 256 n per block (full N => A fetched exactly once).
// AMODE: 0 = A bf16 (global_load_lds), 1 = A f32 (register-convert staging)
template <int AMODE>
__global__ void proj_gemm(const void* __restrict__ Apv, const unsigned short* __restrict__ Bt,
                          unsigned short* __restrict__ C, int K, int lda) {
  __shared__ unsigned short As[64 * 32];    // 4 KB
  __shared__ unsigned short Bs[256 * 32];   // 16 KB

  const int m0   = blockIdx.x * 64;
  const int t    = threadIdx.x;
  const int lane = t & 63;
  const int wave = t >> 6;
  const int wn   = wave * 64;
  const int r16  = lane & 15;
  const int q    = lane >> 4;

  const unsigned short* Abf = (const unsigned short*)Apv;
  const float* A32 = (const float*)Apv;

  floatx4 acc[4][4];
#pragma unroll
  for (int i = 0; i < 4; ++i)
#pragma unroll
    for (int j = 0; j < 4; ++j) acc[i][j] = (floatx4){0.f, 0.f, 0.f, 0.f};

  for (int kt = 0; kt < K; kt += 32) {
    __syncthreads();
#pragma unroll
    for (int cc = 0; cc < 4; ++cc) {
      int c = t + cc * 256;
      gload_lds16(Bt + (size_t)(c >> 2) * K + kt + (c & 3) * 8, &Bs[c * 8]);
    }
    if constexpr (AMODE == 0) {
      gload_lds16(Abf + (size_t)(m0 + (t >> 2)) * lda + kt + (t & 3) * 8, &As[t * 8]);
    } else {
      const float* g = A32 + (size_t)(m0 + (t >> 2)) * lda + kt + (t & 3) * 8;
      float4 v0 = *(const float4*)g;
      float4 v1 = *(const float4*)(g + 4);
      short8 p;
      p[0] = (short)f2b(v0.x); p[1] = (short)f2b(v0.y);
      p[2] = (short)f2b(v0.z); p[3] = (short)f2b(v0.w);
      p[4] = (short)f2b(v1.x); p[5] = (short)f2b(v1.y);
      p[6] = (short)f2b(v1.z); p[7] = (short)f2b(v1.w);
      *(short8*)&As[t * 8] = p;
    }
    __syncthreads();

    bf16x8 af[4], bfr[4];
#pragma unroll
    for (int i = 0; i < 4; ++i) af[i]  = *(const bf16x8*)&As[(i * 16 + r16) * 32 + q * 8];
#pragma unroll
    for (int j = 0; j < 4; ++j) bfr[j] = *(const bf16x8*)&Bs[(wn + j * 16 + r16) * 32 + q * 8];
#pragma unroll
    for (int i = 0; i < 4; ++i)
#pragma unroll
      for (int j = 0; j < 4; ++j)
        acc[i][j] = __builtin_amdgcn_mfma_f32_16x16x32_bf16(af[i], bfr[j], acc[i][j], 0, 0, 0);
  }

#pragma unroll
  for (int i = 0; i < 4; ++i) {
#pragma unroll
    for (int r = 0; r < 4; ++r) {
      int m = m0 + i * 16 + q * 4 + r;
#pragma unroll
      for (int j = 0; j < 4; ++j) {
        int n = wn + j * 16 + r16;
        C[(size_t)m * 256 + n] = f2b(acc[i][j][r]);
      }
    }
  }
}

// ---------- NT GEMM, 128x128 tile, XCD-swizzled 1D grid ----------
// Block decode: xcd = g&7 owns batches {xcd*2, xcd*2+1} (B=16, 8 XCDs, round-robin dispatch heuristic).
// EPI 1: C=bf16 exp(v*escale), atomicAdd row sums.  EPI 2: C=f32 v/sums[row].
template <int EPI>
__global__ void gemm_nt(const unsigned short* __restrict__ Ab, const unsigned short* __restrict__ Btb,
                        void* __restrict__ Cpv, float* __restrict__ sums,
                        int K, int lda, int ldb, int ldc,
                        long long sA, long long sB, long long sC, int sstride,
                        float escale, int nx, int tiles_pb) {
  __shared__ unsigned short As[128 * 32];
  __shared__ unsigned short Bs[128 * 32];

  const int g   = blockIdx.x;
  const int xcd = g & 7;
  const int jj  = g >> 3;
  const int bz  = xcd * 2 + jj / tiles_pb;
  const int tt  = jj % tiles_pb;
  const int m0  = (tt / nx) * 128;
  const int n0  = (tt % nx) * 128;

  const int t    = threadIdx.x;
  const int lane = t & 63;
  const int wave = t >> 6;
  const int wm   = (wave & 1) * 64;
  const int wn   = (wave >> 1) * 64;
  const int r16  = lane & 15;
  const int q    = lane >> 4;

  const unsigned short* Bt = Btb + (long long)bz * sB;
  const unsigned short* A  = Ab + (long long)bz * sA;

  floatx4 acc[4][4];
#pragma unroll
  for (int i = 0; i < 4; ++i)
#pragma unroll
    for (int j = 0; j < 4; ++j) acc[i][j] = (floatx4){0.f, 0.f, 0.f, 0.f};

  for (int kt = 0; kt < K; kt += 32) {
    __syncthreads();
#pragma unroll
    for (int cc = 0; cc < 2; ++cc) {
      int c = t + cc * 256;
      gload_lds16(Bt + (size_t)(n0 + (c >> 2)) * ldb + kt + (c & 3) * 8, &Bs[c * 8]);
    }
#pragma unroll
    for (int cc = 0; cc < 2; ++cc) {
      int c = t + cc * 256;
      gload_lds16(A + (size_t)(m0 + (c >> 2)) * lda + kt + (c & 3) * 8, &As[c * 8]);
    }
    __syncthreads();

    bf16x8 af[4], bfr[4];
#pragma unroll
    for (int i = 0; i < 4; ++i) af[i]  = *(const bf16x8*)&As[(wm + i * 16 + r16) * 32 + q * 8];
#pragma unroll
    for (int j = 0; j < 4; ++j) bfr[j] = *(const bf16x8*)&Bs[(wn + j * 16 + r16) * 32 + q * 8];
#pragma unroll
    for (int i = 0; i < 4; ++i)
#pragma unroll
      for (int j = 0; j < 4; ++j)
        acc[i][j] = __builtin_amdgcn_mfma_f32_16x16x32_bf16(af[i], bfr[j], acc[i][j], 0, 0, 0);
  }

  if constexpr (EPI == 1) {
    unsigned short* C = (unsigned short*)Cpv + (long long)bz * sC;
#pragma unroll
    for (int i = 0; i < 4; ++i) {
#pragma unroll
      for (int r = 0; r < 4; ++r) {
        int m = m0 + wm + i * 16 + q * 4 + r;
        float ps = 0.f;
#pragma unroll
        for (int j = 0; j < 4; ++j) {
          int n = n0 + wn + j * 16 + r16;
          float v = __expf(acc[i][j][r] * escale);
          ps += v;
          C[(size_t)m * ldc + n] = f2b(v);
        }
        // reduce over the 16 lanes sharing this row (masks <16 stay in-group)
#pragma unroll
        for (int msk = 1; msk < 16; msk <<= 1) ps += __shfl_xor(ps, msk, 64);
        if (r16 == 0) atomicAdd(&sums[(long long)bz * sstride + m], ps);
      }
    }
  } else {
    float* C = (float*)Cpv + (long long)bz * sC;
    const float* sb = sums + (long long)bz * sstride;
#pragma unroll
    for (int i = 0; i < 4; ++i) {
#pragma unroll
      for (int r = 0; r < 4; ++r) {
        int m = m0 + wm + i * 16 + q * 4 + r;
        float sc = 1.0f / sb[m];
#pragma unroll
        for (int j = 0; j < 4; ++j) {
          int n = n0 + wn + j * 16 + r16;
          C[(size_t)m * ldc + n] = acc[i][j][r] * sc;
        }
      }
    }
  }
}

// ---------- launch ----------
extern "C" void kernel_launch(void* const* d_in, const int* in_sizes, int n_in,
                              void* d_out, int out_size, void* d_ws, size_t ws_size,
                              hipStream_t stream) {
  (void)in_sizes; (void)n_in; (void)out_size; (void)ws_size;
  const float* H  = (const float*)d_in[0];   // [16][2048][1280]
  const float* G  = (const float*)d_in[1];   // [16][512][768]
  const float* Wq = (const float*)d_in[2];   // [256][768]
  const float* Wk = (const float*)d_in[3];   // [256][1280]
  float* Z = (float*)d_out;                  // [16][512][1280]

  constexpr int B = 16, L = 2048, Dh = 1280, T = 512, Dg = 768, P = 256;

  char* ws = (char*)d_ws;
  size_t off = 0;
  auto alloc = [&](size_t bytes) { void* p = ws + off; off += (bytes + 255) & ~(size_t)255; return p; };
  unsigned short* Gbf  = (unsigned short*)alloc((size_t)B * T * Dg * 2);   // 12.6 MB
  unsigned short* Wqbf = (unsigned short*)alloc((size_t)P * Dg * 2);
  unsigned short* Wkbf = (unsigned short*)alloc((size_t)P * Dh * 2);
  unsigned short* Qbf  = (unsigned short*)alloc((size_t)B * T * P * 2);    // 4 MB
  unsigned short* Kbf  = (unsigned short*)alloc((size_t)B * L * P * 2);    // 16 MB
  unsigned short* HT   = (unsigned short*)alloc((size_t)B * Dh * L * 2);   // 80 MB
  unsigned short* E    = (unsigned short*)alloc((size_t)B * T * L * 2);    // 32 MB
  float*          sums = (float*)alloc((size_t)B * T * 4);
  // total ~145 MB of ws

  // converts (fused) + sums zero-init + transpose
  {
    int na4 = B * T * Dg / 4, nb4 = P * Dg / 4, nc4 = P * Dh / 4;
    cvt3_kernel<<<(na4 + nb4 + nc4 + 255) / 256, 256, 0, stream>>>(
        G, Gbf, na4, Wq, Wqbf, nb4, Wk, Wkbf, nc4);
  }
  zero_kernel<<<(B * T + 255) / 256, 256, 0, stream>>>(sums, B * T);
  transpose_cvt_H<<<dim3(L / 64, Dh / 64, B), 256, 0, stream>>>(H, HT);

  // Q = Gbf * Wqbf^T : [8192][256]
  proj_gemm<0><<<B * T / 64, 256, 0, stream>>>(Gbf, Wqbf, Qbf, Dg, Dg);
  // K = H(f32) * Wkbf^T : [32768][256], H fetched once
  proj_gemm<1><<<B * L / 64, 256, 0, stream>>>(H, Wkbf, Kbf, Dh, Dh);

  // E = exp(scale * Qb * Kb^T) + row sums : per b [512][2048], 64 tiles/batch
  gemm_nt<1><<<B * (T / 128) * (L / 128), 256, 0, stream>>>(
      Qbf, Kbf, E, sums, P, P, P, L,
      (long long)T * P, (long long)L * P, (long long)T * L, T,
      0.0625f, L / 128, (T / 128) * (L / 128));

  // Z = diag(1/sums) * Eb * HTb^T : per b [512][1280] f32, 40 tiles/batch
  gemm_nt<2><<<B * (T / 128) * (Dh / 128), 256, 0, stream>>>(
      E, HT, Z, sums, L, L, L, Dh,
      (long long)T * L, (long long)Dh * L, (long long)T * Dh, T,
      0.f, Dh / 128, (T / 128) * (Dh / 128));
}

// Round 4
// 412.029 us; speedup vs baseline: 1.1642x; 1.0780x over previous
//
#include <hip/hip_runtime.h>
#include <stdint.h>

// ---------- types ----------
typedef __attribute__((ext_vector_type(8))) short   short8;
typedef __attribute__((ext_vector_type(8))) __bf16  bf16x8;
typedef __attribute__((ext_vector_type(4))) float   floatx4;

#define DEV static __device__ __forceinline__

// f32 -> bf16 (RNE) raw bits
DEV unsigned short f2b(float f) {
  union { float f; unsigned u; } v; v.f = f;
  unsigned u = v.u;
  unsigned r = u + 0x7FFFu + ((u >> 16) & 1u);
  return (unsigned short)(r >> 16);
}

// async global->LDS, 16 bytes per lane. LDS dest must be wave-uniform base + lane*16.
DEV void gload_lds16(const void* g, void* l) {
  __builtin_amdgcn_global_load_lds(
      (const __attribute__((address_space(1))) unsigned int*)g,
      (__attribute__((address_space(3))) unsigned int*)l,
      16, 0, 0);
}

// ---------- weights f32->bf16 convert + sums zero-init ----------
__global__ void cvtw_kernel(const float* __restrict__ a, unsigned short* __restrict__ oa, int na4,
                            const float* __restrict__ b, unsigned short* __restrict__ ob, int nb4,
                            float* __restrict__ zp, int nz) {
  int i = blockIdx.x * blockDim.x + threadIdx.x;
  if (i < na4) {
    float4 v = ((const float4*)a)[i];
    ushort4 o; o.x = f2b(v.x); o.y = f2b(v.y); o.z = f2b(v.z); o.w = f2b(v.w);
    ((ushort4*)oa)[i] = o;
  } else if (i < na4 + nb4) {
    int k = i - na4;
    float4 v = ((const float4*)b)[k];
    ushort4 o; o.x = f2b(v.x); o.y = f2b(v.y); o.z = f2b(v.z); o.w = f2b(v.w);
    ((ushort4*)ob)[k] = o;
  } else if (i < na4 + nb4 + nz) {
    zp[i - na4 - nb4] = 0.f;
  }
}

// ---------- projection GEMM: C[M][256] = A[M][K] * Bt[256][K]^T ----------
// 64 m x 256 n per block (full N => A fetched exactly once).
// A is f32, converted to bf16 in registers during staging.
// WRITE_HT: also emit the staged A tile transposed to HT [16][K][2048] bf16
// (used by K-proj: A rows are (b*2048+l), cols are d; HT[b][d][l]).
template <int WRITE_HT>
__global__ void proj_gemm(const float* __restrict__ A32, const unsigned short* __restrict__ Bt,
                          unsigned short* __restrict__ C, unsigned short* __restrict__ HT,
                          int K, int lda) {
  __shared__ unsigned short As[64 * 32];    // 4 KB
  __shared__ unsigned short Bs[256 * 32];   // 16 KB

  const int m0   = blockIdx.x * 64;
  const int t    = threadIdx.x;
  const int lane = t & 63;
  const int wave = t >> 6;
  const int wn   = wave * 64;
  const int r16  = lane & 15;
  const int q    = lane >> 4;

  floatx4 acc[4][4];
#pragma unroll
  for (int i = 0; i < 4; ++i)
#pragma unroll
    for (int j = 0; j < 4; ++j) acc[i][j] = (floatx4){0.f, 0.f, 0.f, 0.f};

  for (int kt = 0; kt < K; kt += 32) {
    __syncthreads();
    // stage B tile [256 n][32 k]: 1024 16B chunks
#pragma unroll
    for (int cc = 0; cc < 4; ++cc) {
      int c = t + cc * 256;
      gload_lds16(Bt + (size_t)(c >> 2) * K + kt + (c & 3) * 8, &Bs[c * 8]);
    }
    // stage A tile [64 m][32 k], f32 -> bf16 register convert
    {
      const float* g = A32 + (size_t)(m0 + (t >> 2)) * lda + kt + (t & 3) * 8;
      float4 v0 = *(const float4*)g;
      float4 v1 = *(const float4*)(g + 4);
      short8 p;
      p[0] = (short)f2b(v0.x); p[1] = (short)f2b(v0.y);
      p[2] = (short)f2b(v0.z); p[3] = (short)f2b(v0.w);
      p[4] = (short)f2b(v1.x); p[5] = (short)f2b(v1.y);
      p[6] = (short)f2b(v1.z); p[7] = (short)f2b(v1.w);
      *(short8*)&As[t * 8] = p;
    }
    __syncthreads();

    bf16x8 af[4], bfr[4];
#pragma unroll
    for (int i = 0; i < 4; ++i) af[i]  = *(const bf16x8*)&As[(i * 16 + r16) * 32 + q * 8];
#pragma unroll
    for (int j = 0; j < 4; ++j) bfr[j] = *(const bf16x8*)&Bs[(wn + j * 16 + r16) * 32 + q * 8];
#pragma unroll
    for (int i = 0; i < 4; ++i)
#pragma unroll
      for (int j = 0; j < 4; ++j)
        acc[i][j] = __builtin_amdgcn_mfma_f32_16x16x32_bf16(af[i], bfr[j], acc[i][j], 0, 0, 0);

    if constexpr (WRITE_HT) {
      // transpose the staged A tile out to HT[b][kt+d][l0 + lc*8 .. +8)
      // decode: d = t>>3 (0..31), lc = t&7 -> per-wave 8 lanes per d-row,
      // giving 128B-contiguous global stores per d-row.
      const int d  = t >> 3;
      const int lc = t & 7;
      short8 v;
#pragma unroll
      for (int j = 0; j < 8; ++j) v[j] = (short)As[(lc * 8 + j) * 32 + d];
      const int b  = m0 >> 11;        // 2048 rows per batch
      const int l0 = m0 & 2047;
      *(short8*)&HT[((size_t)b * 1280 + kt + d) * 2048 + l0 + lc * 8] = v;
    }
  }

  // epilogue: bf16 store, ldc = 256
#pragma unroll
  for (int i = 0; i < 4; ++i) {
#pragma unroll
    for (int r = 0; r < 4; ++r) {
      int m = m0 + i * 16 + q * 4 + r;
#pragma unroll
      for (int j = 0; j < 4; ++j) {
        int n = wn + j * 16 + r16;
        C[(size_t)m * 256 + n] = f2b(acc[i][j][r]);
      }
    }
  }
}

// ---------- NT GEMM, 128x128 tile, XCD-swizzled 1D grid ----------
// Block decode: xcd = g&7 owns batches {xcd*2, xcd*2+1} (B=16, 8 XCDs).
// EPI 1: C=bf16 exp(v*escale), atomicAdd row sums.  EPI 2: C=f32 v/sums[row].
template <int EPI>
__global__ void gemm_nt(const unsigned short* __restrict__ Ab, const unsigned short* __restrict__ Btb,
                        void* __restrict__ Cpv, float* __restrict__ sums,
                        int K, int lda, int ldb, int ldc,
                        long long sA, long long sB, long long sC, int sstride,
                        float escale, int nx, int tiles_pb) {
  __shared__ unsigned short As[128 * 32];
  __shared__ unsigned short Bs[128 * 32];

  const int g   = blockIdx.x;
  const int xcd = g & 7;
  const int jj  = g >> 3;
  const int bz  = xcd * 2 + jj / tiles_pb;
  const int tt  = jj % tiles_pb;
  const int m0  = (tt / nx) * 128;
  const int n0  = (tt % nx) * 128;

  const int t    = threadIdx.x;
  const int lane = t & 63;
  const int wave = t >> 6;
  const int wm   = (wave & 1) * 64;
  const int wn   = (wave >> 1) * 64;
  const int r16  = lane & 15;
  const int q    = lane >> 4;

  const unsigned short* Bt = Btb + (long long)bz * sB;
  const unsigned short* A  = Ab + (long long)bz * sA;

  floatx4 acc[4][4];
#pragma unroll
  for (int i = 0; i < 4; ++i)
#pragma unroll
    for (int j = 0; j < 4; ++j) acc[i][j] = (floatx4){0.f, 0.f, 0.f, 0.f};

  for (int kt = 0; kt < K; kt += 32) {
    __syncthreads();
#pragma unroll
    for (int cc = 0; cc < 2; ++cc) {
      int c = t + cc * 256;
      gload_lds16(Bt + (size_t)(n0 + (c >> 2)) * ldb + kt + (c & 3) * 8, &Bs[c * 8]);
    }
#pragma unroll
    for (int cc = 0; cc < 2; ++cc) {
      int c = t + cc * 256;
      gload_lds16(A + (size_t)(m0 + (c >> 2)) * lda + kt + (c & 3) * 8, &As[c * 8]);
    }
    __syncthreads();

    bf16x8 af[4], bfr[4];
#pragma unroll
    for (int i = 0; i < 4; ++i) af[i]  = *(const bf16x8*)&As[(wm + i * 16 + r16) * 32 + q * 8];
#pragma unroll
    for (int j = 0; j < 4; ++j) bfr[j] = *(const bf16x8*)&Bs[(wn + j * 16 + r16) * 32 + q * 8];
#pragma unroll
    for (int i = 0; i < 4; ++i)
#pragma unroll
      for (int j = 0; j < 4; ++j)
        acc[i][j] = __builtin_amdgcn_mfma_f32_16x16x32_bf16(af[i], bfr[j], acc[i][j], 0, 0, 0);
  }

  if constexpr (EPI == 1) {
    unsigned short* C = (unsigned short*)Cpv + (long long)bz * sC;
#pragma unroll
    for (int i = 0; i < 4; ++i) {
#pragma unroll
      for (int r = 0; r < 4; ++r) {
        int m = m0 + wm + i * 16 + q * 4 + r;
        float ps = 0.f;
#pragma unroll
        for (int j = 0; j < 4; ++j) {
          int n = n0 + wn + j * 16 + r16;
          float v = __expf(acc[i][j][r] * escale);
          ps += v;
          C[(size_t)m * ldc + n] = f2b(v);
        }
        // reduce over the 16 lanes sharing this row
#pragma unroll
        for (int msk = 1; msk < 16; msk <<= 1) ps += __shfl_xor(ps, msk, 64);
        if (r16 == 0) atomicAdd(&sums[(long long)bz * sstride + m], ps);
      }
    }
  } else {
    float* C = (float*)Cpv + (long long)bz * sC;
    const float* sb = sums + (long long)bz * sstride;
#pragma unroll
    for (int i = 0; i < 4; ++i) {
#pragma unroll
      for (int r = 0; r < 4; ++r) {
        int m = m0 + wm + i * 16 + q * 4 + r;
        float sc = 1.0f / sb[m];
#pragma unroll
        for (int j = 0; j < 4; ++j) {
          int n = n0 + wn + j * 16 + r16;
          C[(size_t)m * ldc + n] = acc[i][j][r] * sc;
        }
      }
    }
  }
}

// ---------- launch ----------
extern "C" void kernel_launch(void* const* d_in, const int* in_sizes, int n_in,
                              void* d_out, int out_size, void* d_ws, size_t ws_size,
                              hipStream_t stream) {
  (void)in_sizes; (void)n_in; (void)out_size; (void)ws_size;
  const float* H  = (const float*)d_in[0];   // [16][2048][1280]
  const float* G  = (const float*)d_in[1];   // [16][512][768]
  const float* Wq = (const float*)d_in[2];   // [256][768]
  const float* Wk = (const float*)d_in[3];   // [256][1280]
  float* Z = (float*)d_out;                  // [16][512][1280]

  constexpr int B = 16, L = 2048, Dh = 1280, T = 512, Dg = 768, P = 256;

  char* ws = (char*)d_ws;
  size_t off = 0;
  auto alloc = [&](size_t bytes) { void* p = ws + off; off += (bytes + 255) & ~(size_t)255; return p; };
  unsigned short* Wqbf = (unsigned short*)alloc((size_t)P * Dg * 2);
  unsigned short* Wkbf = (unsigned short*)alloc((size_t)P * Dh * 2);
  unsigned short* Qbf  = (unsigned short*)alloc((size_t)B * T * P * 2);    // 4 MB
  unsigned short* Kbf  = (unsigned short*)alloc((size_t)B * L * P * 2);    // 16 MB
  unsigned short* HT   = (unsigned short*)alloc((size_t)B * Dh * L * 2);   // 80 MB
  unsigned short* E    = (unsigned short*)alloc((size_t)B * T * L * 2);    // 32 MB
  float*          sums = (float*)alloc((size_t)B * T * 4);
  // total ~132 MB of ws

  // weights convert + sums zero-init (one small kernel)
  {
    int na4 = P * Dg / 4, nb4 = P * Dh / 4, nz = B * T;
    cvtw_kernel<<<(na4 + nb4 + nz + 255) / 256, 256, 0, stream>>>(
        Wq, Wqbf, na4, Wk, Wkbf, nb4, sums, nz);
  }

  // Q = G(f32) * Wqbf^T : [8192][256], G fetched once
  proj_gemm<0><<<B * T / 64, 256, 0, stream>>>(G, Wqbf, Qbf, nullptr, Dg, Dg);
  // K = H(f32) * Wkbf^T : [32768][256], H fetched once; also emits HT bf16
  proj_gemm<1><<<B * L / 64, 256, 0, stream>>>(H, Wkbf, Kbf, HT, Dh, Dh);

  // E = exp(scale * Qb * Kb^T) + row sums : per b [512][2048], 64 tiles/batch
  gemm_nt<1><<<B * (T / 128) * (L / 128), 256, 0, stream>>>(
      Qbf, Kbf, E, sums, P, P, P, L,
      (long long)T * P, (long long)L * P, (long long)T * L, T,
      0.0625f, L / 128, (T / 128) * (L / 128));

  // Z = diag(1/sums) * Eb * HTb^T : per b [512][1280] f32, 40 tiles/batch
  gemm_nt<2><<<B * (T / 128) * (Dh / 128), 256, 0, stream>>>(
      E, HT, Z, sums, L, L, L, Dh,
      (long long)T * L, (long long)Dh * L, (long long)T * Dh, T,
      0.f, Dh / 128, (T / 128) * (Dh / 128));
}

// Round 5
// 411.670 us; speedup vs baseline: 1.1653x; 1.0009x over previous
//
#include <hip/hip_runtime.h>
#include <stdint.h>

// ---------- types ----------
typedef __attribute__((ext_vector_type(8))) short   short8;
typedef __attribute__((ext_vector_type(8))) __bf16  bf16x8;
typedef __attribute__((ext_vector_type(4))) float   floatx4;

#define DEV static __device__ __forceinline__

// f32 -> bf16 (RNE) raw bits
DEV unsigned short f2b(float f) {
  union { float f; unsigned u; } v; v.f = f;
  unsigned u = v.u;
  unsigned r = u + 0x7FFFu + ((u >> 16) & 1u);
  return (unsigned short)(r >> 16);
}

// async global->LDS, 16 bytes per lane. LDS dest must be wave-uniform base + lane*16.
DEV void gload_lds16(const void* g, void* l) {
  __builtin_amdgcn_global_load_lds(
      (const __attribute__((address_space(1))) unsigned int*)g,
      (__attribute__((address_space(3))) unsigned int*)l,
      16, 0, 0);
}

// ---------- weights f32->bf16 convert + sums zero-init ----------
__global__ void cvtw_kernel(const float* __restrict__ a, unsigned short* __restrict__ oa, int na4,
                            const float* __restrict__ b, unsigned short* __restrict__ ob, int nb4,
                            float* __restrict__ zp, int nz) {
  int i = blockIdx.x * blockDim.x + threadIdx.x;
  if (i < na4) {
    float4 v = ((const float4*)a)[i];
    ushort4 o; o.x = f2b(v.x); o.y = f2b(v.y); o.z = f2b(v.z); o.w = f2b(v.w);
    ((ushort4*)oa)[i] = o;
  } else if (i < na4 + nb4) {
    int k = i - na4;
    float4 v = ((const float4*)b)[k];
    ushort4 o; o.x = f2b(v.x); o.y = f2b(v.y); o.z = f2b(v.z); o.w = f2b(v.w);
    ((ushort4*)ob)[k] = o;
  } else if (i < na4 + nb4 + nz) {
    zp[i - na4 - nb4] = 0.f;
  }
}

// ---------- projection GEMM: C[M][256] = A[M][K] * Bt[256][K]^T ----------
// 64 m x 256 n per block (full N => A fetched exactly once).
// A is f32, converted to bf16 in registers during staging.
// WRITE_HT: also emit the staged A tile transposed to HT [16][K][2048] bf16.
// Transpose path uses At2 [32 k][66 l] (stride 66 shorts = 33 words, odd =>
// writes cover all 32 banks; reads are 4x b32, 2-way aliasing = free).
template <int WRITE_HT>
__global__ void proj_gemm(const float* __restrict__ A32, const unsigned short* __restrict__ Bt,
                          unsigned short* __restrict__ C, unsigned short* __restrict__ HT,
                          int K, int lda) {
  __shared__ unsigned short As[64 * 32];    // 4 KB
  __shared__ unsigned short Bs[256 * 32];   // 16 KB
  __shared__ unsigned short At2[WRITE_HT ? 32 * 66 : 1];  // 4.2 KB (transposed copy)

  const int m0   = blockIdx.x * 64;
  const int t    = threadIdx.x;
  const int lane = t & 63;
  const int wave = t >> 6;
  const int wn   = wave * 64;
  const int r16  = lane & 15;
  const int q    = lane >> 4;

  floatx4 acc[4][4];
#pragma unroll
  for (int i = 0; i < 4; ++i)
#pragma unroll
    for (int j = 0; j < 4; ++j) acc[i][j] = (floatx4){0.f, 0.f, 0.f, 0.f};

  for (int kt = 0; kt < K; kt += 32) {
    __syncthreads();
    // stage B tile [256 n][32 k]: 1024 16B chunks
#pragma unroll
    for (int cc = 0; cc < 4; ++cc) {
      int c = t + cc * 256;
      gload_lds16(Bt + (size_t)(c >> 2) * K + kt + (c & 3) * 8, &Bs[c * 8]);
    }
    // stage A tile [64 m][32 k], f32 -> bf16 register convert
    {
      const int row = t >> 2;
      const int seg = t & 3;
      const float* g = A32 + (size_t)(m0 + row) * lda + kt + seg * 8;
      float4 v0 = *(const float4*)g;
      float4 v1 = *(const float4*)(g + 4);
      short8 p;
      p[0] = (short)f2b(v0.x); p[1] = (short)f2b(v0.y);
      p[2] = (short)f2b(v0.z); p[3] = (short)f2b(v0.w);
      p[4] = (short)f2b(v1.x); p[5] = (short)f2b(v1.y);
      p[6] = (short)f2b(v1.z); p[7] = (short)f2b(v1.w);
      *(short8*)&As[t * 8] = p;
      if constexpr (WRITE_HT) {
        // transposed copy: At2[k][l], k = seg*8+j, l = row.
        // bank = (8*seg + j + row/2) mod 32 -> conflict-free per step j.
#pragma unroll
        for (int j = 0; j < 8; ++j)
          At2[(seg * 8 + j) * 66 + row] = (unsigned short)p[j];
      }
    }
    __syncthreads();

    bf16x8 af[4], bfr[4];
#pragma unroll
    for (int i = 0; i < 4; ++i) af[i]  = *(const bf16x8*)&As[(i * 16 + r16) * 32 + q * 8];
#pragma unroll
    for (int j = 0; j < 4; ++j) bfr[j] = *(const bf16x8*)&Bs[(wn + j * 16 + r16) * 32 + q * 8];
#pragma unroll
    for (int i = 0; i < 4; ++i)
#pragma unroll
      for (int j = 0; j < 4; ++j)
        acc[i][j] = __builtin_amdgcn_mfma_f32_16x16x32_bf16(af[i], bfr[j], acc[i][j], 0, 0, 0);

    if constexpr (WRITE_HT) {
      // read back conflict-free: thread (d = t>>3, lc = t&7) reads
      // At2[d][lc*8 .. +8] as 4x b32 (word = d*33 + lc*4 + c; banks 2-way).
      const int d  = t >> 3;
      const int lc = t & 7;
      const unsigned* w = (const unsigned*)At2 + d * 33 + lc * 4;
      union { unsigned u[4]; short8 s; } vv;
      vv.u[0] = w[0]; vv.u[1] = w[1]; vv.u[2] = w[2]; vv.u[3] = w[3];
      const int b  = m0 >> 11;        // 2048 rows per batch
      const int l0 = m0 & 2047;
      *(short8*)&HT[((size_t)b * 1280 + kt + d) * 2048 + l0 + lc * 8] = vv.s;
    }
  }

  // epilogue: bf16 store, ldc = 256
#pragma unroll
  for (int i = 0; i < 4; ++i) {
#pragma unroll
    for (int r = 0; r < 4; ++r) {
      int m = m0 + i * 16 + q * 4 + r;
#pragma unroll
      for (int j = 0; j < 4; ++j) {
        int n = wn + j * 16 + r16;
        C[(size_t)m * 256 + n] = f2b(acc[i][j][r]);
      }
    }
  }
}

// ---------- NT GEMM, 128x128 tile, XCD-swizzled 1D grid ----------
// Block decode: xcd = g&7 owns batches {xcd*2, xcd*2+1} (B=16, 8 XCDs).
// EPI 1: C=bf16 exp(v*escale), atomicAdd row sums.  EPI 2: C=f32 v/sums[row].
template <int EPI>
__global__ void gemm_nt(const unsigned short* __restrict__ Ab, const unsigned short* __restrict__ Btb,
                        void* __restrict__ Cpv, float* __restrict__ sums,
                        int K, int lda, int ldb, int ldc,
                        long long sA, long long sB, long long sC, int sstride,
                        float escale, int nx, int tiles_pb) {
  __shared__ unsigned short As[128 * 32];
  __shared__ unsigned short Bs[128 * 32];

  const int g   = blockIdx.x;
  const int xcd = g & 7;
  const int jj  = g >> 3;
  const int bz  = xcd * 2 + jj / tiles_pb;
  const int tt  = jj % tiles_pb;
  const int m0  = (tt / nx) * 128;
  const int n0  = (tt % nx) * 128;

  const int t    = threadIdx.x;
  const int lane = t & 63;
  const int wave = t >> 6;
  const int wm   = (wave & 1) * 64;
  const int wn   = (wave >> 1) * 64;
  const int r16  = lane & 15;
  const int q    = lane >> 4;

  const unsigned short* Bt = Btb + (long long)bz * sB;
  const unsigned short* A  = Ab + (long long)bz * sA;

  floatx4 acc[4][4];
#pragma unroll
  for (int i = 0; i < 4; ++i)
#pragma unroll
    for (int j = 0; j < 4; ++j) acc[i][j] = (floatx4){0.f, 0.f, 0.f, 0.f};

  for (int kt = 0; kt < K; kt += 32) {
    __syncthreads();
#pragma unroll
    for (int cc = 0; cc < 2; ++cc) {
      int c = t + cc * 256;
      gload_lds16(Bt + (size_t)(n0 + (c >> 2)) * ldb + kt + (c & 3) * 8, &Bs[c * 8]);
    }
#pragma unroll
    for (int cc = 0; cc < 2; ++cc) {
      int c = t + cc * 256;
      gload_lds16(A + (size_t)(m0 + (c >> 2)) * lda + kt + (c & 3) * 8, &As[c * 8]);
    }
    __syncthreads();

    bf16x8 af[4], bfr[4];
#pragma unroll
    for (int i = 0; i < 4; ++i) af[i]  = *(const bf16x8*)&As[(wm + i * 16 + r16) * 32 + q * 8];
#pragma unroll
    for (int j = 0; j < 4; ++j) bfr[j] = *(const bf16x8*)&Bs[(wn + j * 16 + r16) * 32 + q * 8];
#pragma unroll
    for (int i = 0; i < 4; ++i)
#pragma unroll
      for (int j = 0; j < 4; ++j)
        acc[i][j] = __builtin_amdgcn_mfma_f32_16x16x32_bf16(af[i], bfr[j], acc[i][j], 0, 0, 0);
  }

  if constexpr (EPI == 1) {
    unsigned short* C = (unsigned short*)Cpv + (long long)bz * sC;
#pragma unroll
    for (int i = 0; i < 4; ++i) {
#pragma unroll
      for (int r = 0; r < 4; ++r) {
        int m = m0 + wm + i * 16 + q * 4 + r;
        float ps = 0.f;
#pragma unroll
        for (int j = 0; j < 4; ++j) {
          int n = n0 + wn + j * 16 + r16;
          float v = __expf(acc[i][j][r] * escale);
          ps += v;
          C[(size_t)m * ldc + n] = f2b(v);
        }
        // reduce over the 16 lanes sharing this row
#pragma unroll
        for (int msk = 1; msk < 16; msk <<= 1) ps += __shfl_xor(ps, msk, 64);
        if (r16 == 0) atomicAdd(&sums[(long long)bz * sstride + m], ps);
      }
    }
  } else {
    float* C = (float*)Cpv + (long long)bz * sC;
    const float* sb = sums + (long long)bz * sstride;
#pragma unroll
    for (int i = 0; i < 4; ++i) {
#pragma unroll
      for (int r = 0; r < 4; ++r) {
        int m = m0 + wm + i * 16 + q * 4 + r;
        float sc = 1.0f / sb[m];
#pragma unroll
        for (int j = 0; j < 4; ++j) {
          int n = n0 + wn + j * 16 + r16;
          C[(size_t)m * ldc + n] = acc[i][j][r] * sc;
        }
      }
    }
  }
}

// ---------- launch ----------
extern "C" void kernel_launch(void* const* d_in, const int* in_sizes, int n_in,
                              void* d_out, int out_size, void* d_ws, size_t ws_size,
                              hipStream_t stream) {
  (void)in_sizes; (void)n_in; (void)out_size; (void)ws_size;
  const float* H  = (const float*)d_in[0];   // [16][2048][1280]
  const float* G  = (const float*)d_in[1];   // [16][512][768]
  const float* Wq = (const float*)d_in[2];   // [256][768]
  const float* Wk = (const float*)d_in[3];   // [256][1280]
  float* Z = (float*)d_out;                  // [16][512][1280]

  constexpr int B = 16, L = 2048, Dh = 1280, T = 512, Dg = 768, P = 256;

  char* ws = (char*)d_ws;
  size_t off = 0;
  auto alloc = [&](size_t bytes) { void* p = ws + off; off += (bytes + 255) & ~(size_t)255; return p; };
  unsigned short* Wqbf = (unsigned short*)alloc((size_t)P * Dg * 2);
  unsigned short* Wkbf = (unsigned short*)alloc((size_t)P * Dh * 2);
  unsigned short* Qbf  = (unsigned short*)alloc((size_t)B * T * P * 2);    // 4 MB
  unsigned short* Kbf  = (unsigned short*)alloc((size_t)B * L * P * 2);    // 16 MB
  unsigned short* HT   = (unsigned short*)alloc((size_t)B * Dh * L * 2);   // 80 MB
  unsigned short* E    = (unsigned short*)alloc((size_t)B * T * L * 2);    // 32 MB
  float*          sums = (float*)alloc((size_t)B * T * 4);
  // total ~132 MB of ws

  // weights convert + sums zero-init (one small kernel)
  {
    int na4 = P * Dg / 4, nb4 = P * Dh / 4, nz = B * T;
    cvtw_kernel<<<(na4 + nb4 + nz + 255) / 256, 256, 0, stream>>>(
        Wq, Wqbf, na4, Wk, Wkbf, nb4, sums, nz);
  }

  // Q = G(f32) * Wqbf^T : [8192][256], G fetched once
  proj_gemm<0><<<B * T / 64, 256, 0, stream>>>(G, Wqbf, Qbf, nullptr, Dg, Dg);
  // K = H(f32) * Wkbf^T : [32768][256], H fetched once; also emits HT bf16
  proj_gemm<1><<<B * L / 64, 256, 0, stream>>>(H, Wkbf, Kbf, HT, Dh, Dh);

  // E = exp(scale * Qb * Kb^T) + row sums : per b [512][2048], 64 tiles/batch
  gemm_nt<1><<<B * (T / 128) * (L / 128), 256, 0, stream>>>(
      Qbf, Kbf, E, sums, P, P, P, L,
      (long long)T * P, (long long)L * P, (long long)T * L, T,
      0.0625f, L / 128, (T / 128) * (L / 128));

  // Z = diag(1/sums) * Eb * HTb^T : per b [512][1280] f32, 40 tiles/batch
  gemm_nt<2><<<B * (T / 128) * (Dh / 128), 256, 0, stream>>>(
      E, HT, Z, sums, L, L, L, Dh,
      (long long)T * L, (long long)Dh * L, (long long)T * Dh, T,
      0.f, Dh / 128, (T / 128) * (Dh / 128));
}